// Round 4
// baseline (40.192 us; speedup 1.0000x reference)
//
#include <hip/hip_runtime.h>

#define NR 700
#define KK 250
#define HID 32

#if __has_builtin(__builtin_amdgcn_exp2f)
#define EXP2F(x) __builtin_amdgcn_exp2f(x)
#else
#define EXP2F(x) exp2f(x)
#endif

// 512 threads = 8 waves/block. Each thread: 4 query rows (slot+64k) x 1/8 of j.
// j-split == wave id -> LDS h reads are wave-uniform broadcasts.
__global__ __launch_bounds__(512, 4) void mlra_kernel(
    const float* __restrict__ power,
    const int*   __restrict__ ele_idx,
    const int*   __restrict__ azi_idx,
    const float* __restrict__ ele_emb,
    const float* __restrict__ azi_emb,
    const float* __restrict__ Wq,
    const float* __restrict__ bq,
    const float* __restrict__ Wk,
    const float* __restrict__ bk,
    const float* __restrict__ Wv,
    const float* __restrict__ bv,
    float* __restrict__ out)
{
    // h rows padded to 8 floats: [x, e0,e1,e2, a0,a1,a2, v]; rows 250..255 = 0
    __shared__ float4 h4[256][2];
    __shared__ float ps[8][256];   // [j-split][row] partial sum-exp
    __shared__ float po[8][256];   // [j-split][row] partial sum-exp*v
    __shared__ float Msh[7][7];
    __shared__ float wsh[7];
    __shared__ float wvsh[8];      // wv[0..6], bv in [7]

    float* hs = reinterpret_cast<float*>(h4);

    const int r    = blockIdx.x;
    const int tid  = threadIdx.x;
    const int slot = tid & 63;    // row slot: rows slot, slot+64, slot+128, slot+192
    const int js   = tid >> 6;    // j-split 0..7 == wave id (wave-uniform)

    // ---- load h rows (one row per thread), zero the pad rows ----
    if (tid < 256) {
        float* hr = hs + tid * 8;
        if (tid < KK) {
            int g = r * KK + tid;
            float x = power[g];
            int ei = ele_idx[g];
            int ai = azi_idx[g];
            hr[0] = x;
            hr[1] = ele_emb[ei * 3 + 0];
            hr[2] = ele_emb[ei * 3 + 1];
            hr[3] = ele_emb[ei * 3 + 2];
            hr[4] = azi_emb[ai * 3 + 0];
            hr[5] = azi_emb[ai * 3 + 1];
            hr[6] = azi_emb[ai * 3 + 2];
            hr[7] = 0.f;
        } else {
            #pragma unroll
            for (int c = 0; c < 8; ++c) hr[c] = 0.f;
        }
    }

    // SCALE * log2(e) folded into the score constants so we can use raw exp2
    const float SC2 = 0.17677669529663687f * 1.4426950408889634f;

    float xout[4];

    for (int l = 0; l < 2; ++l) {
        // ---- per-layer constants: M = SC2*Wq Wk^T (7x7), w = SC2*bq Wk^T, wv, bv ----
        const float* wq = Wq + l * 7 * HID;
        const float* wk = Wk + l * 7 * HID;
        if (tid < 49) {
            int c = tid / 7, cp = tid % 7;
            float s = 0.f;
            #pragma unroll 8
            for (int d = 0; d < HID; ++d) s = fmaf(wq[c * HID + d], wk[cp * HID + d], s);
            Msh[c][cp] = s * SC2;
        } else if (tid < 56) {
            int cp = tid - 49;
            float s = 0.f;
            #pragma unroll 8
            for (int d = 0; d < HID; ++d) s = fmaf(bq[l * HID + d], wk[cp * HID + d], s);
            wsh[cp] = s * SC2;
        } else if (tid < 63) {
            wvsh[tid - 56] = Wv[l * 7 + (tid - 56)];
        } else if (tid == 63) {
            wvsh[7] = bv[l];
        }
        __syncthreads();   // (a) constants ready; h stable

        // ---- per-row t-vectors (4 rows) and v (js==0 writes v) ----
        float t[4][7];
        #pragma unroll
        for (int k = 0; k < 4; ++k) {
            const int row = slot + 64 * k;
            float4 a = h4[row][0], b = h4[row][1];
            float hv[7] = {a.x, a.y, a.z, a.w, b.x, b.y, b.z};
            #pragma unroll
            for (int cp = 0; cp < 7; ++cp) {
                float s = wsh[cp];
                #pragma unroll
                for (int c = 0; c < 7; ++c) s = fmaf(hv[c], Msh[c][cp], s);
                t[k][cp] = s;
            }
            if (js == 0 && row < KK) {
                float v = wvsh[7];
                #pragma unroll
                for (int c = 0; c < 7; ++c) v = fmaf(hv[c], wvsh[c], v);
                hs[row * 8 + 7] = v;
            }
        }
        __syncthreads();   // (b) v visible

        // ---- main loop: 32 iters over j = js + 8*it (wave-uniform broadcast reads) ----
        float ss[4] = {0.f, 0.f, 0.f, 0.f};
        float oo[4] = {0.f, 0.f, 0.f, 0.f};
        #pragma unroll 4
        for (int it = 0; it < 32; ++it) {
            const int j = js + 8 * it;
            float4 ha = h4[j][0];
            float4 hb = h4[j][1];
            #pragma unroll
            for (int k = 0; k < 4; ++k) {
                float sc = fmaf(hb.z, t[k][6], fmaf(hb.y, t[k][5], fmaf(hb.x, t[k][4],
                           fmaf(ha.w, t[k][3], fmaf(ha.z, t[k][2], fmaf(ha.y, t[k][1],
                           ha.x * t[k][0]))))));
                float p = EXP2F(sc);
                ss[k] += p;
                oo[k] = fmaf(p, hb.w, oo[k]);
            }
        }
        // pad correction: js>=2 visited exactly one padded j (score=0 -> p=1)
        const float corr = (js >= 2) ? 1.0f : 0.0f;
        #pragma unroll
        for (int k = 0; k < 4; ++k) {
            const int row = slot + 64 * k;
            ps[js][row] = ss[k] - corr;
            po[js][row] = oo[k];
        }
        __syncthreads();   // (c) partials ready

        // ---- combine splits (wave 0 only), finalize row outputs ----
        if (js == 0) {
            #pragma unroll
            for (int k = 0; k < 4; ++k) {
                const int row = slot + 64 * k;
                float s = ((ps[0][row] + ps[1][row]) + (ps[2][row] + ps[3][row]))
                        + ((ps[4][row] + ps[5][row]) + (ps[6][row] + ps[7][row]));
                float o = ((po[0][row] + po[1][row]) + (po[2][row] + po[3][row]))
                        + ((po[4][row] + po[5][row]) + (po[6][row] + po[7][row]));
                float x = o / s;
                xout[k] = x;
                if (l == 0 && row < KK) hs[row * 8 + 0] = x;  // feed layer-1 input
            }
        }
        // next layer's barrier (a) publishes the h[row][0] update
    }

    if (js == 0) {
        #pragma unroll
        for (int k = 0; k < 4; ++k) {
            const int row = slot + 64 * k;
            if (row < KK) out[r * KK + row] = xout[k];
        }
    }
}

extern "C" void kernel_launch(void* const* d_in, const int* in_sizes, int n_in,
                              void* d_out, int out_size, void* d_ws, size_t ws_size,
                              hipStream_t stream) {
    const float* power   = (const float*)d_in[0];
    const int*   ele     = (const int*)d_in[1];
    const int*   azi     = (const int*)d_in[2];
    const float* ele_emb = (const float*)d_in[3];
    const float* azi_emb = (const float*)d_in[4];
    const float* Wq      = (const float*)d_in[5];
    const float* bq      = (const float*)d_in[6];
    const float* Wk      = (const float*)d_in[7];
    const float* bk      = (const float*)d_in[8];
    const float* Wv      = (const float*)d_in[9];
    const float* bv      = (const float*)d_in[10];
    float* outp = (float*)d_out;

    hipLaunchKernelGGL(mlra_kernel, dim3(NR), dim3(512), 0, stream,
                       power, ele, azi, ele_emb, azi_emb, Wq, bq, Wk, bk, Wv, bv, outp);
}

// Round 5
// 40.145 us; speedup vs baseline: 1.0012x; 1.0012x over previous
//
#include <hip/hip_runtime.h>

#define NR 700
#define KK 250
#define HID 32

typedef _Float16 h2 __attribute__((ext_vector_type(2)));

#if __has_builtin(__builtin_amdgcn_fdot2)
#define FDOT2(a, b, c) __builtin_amdgcn_fdot2((a), (b), (c), false)
#else
#define FDOT2(a, b, c) fmaf((float)(a).x, (float)(b).x, fmaf((float)(a).y, (float)(b).y, (c)))
#endif

#if __has_builtin(__builtin_amdgcn_exp2f)
#define EXP2F(x) __builtin_amdgcn_exp2f(x)
#else
#define EXP2F(x) exp2f(x)
#endif

__device__ __forceinline__ void compute_weights(
    int wt, int l,
    const float* __restrict__ Wq, const float* __restrict__ bq,
    const float* __restrict__ Wk, const float* __restrict__ bk,
    const float* __restrict__ Wv, const float* __restrict__ bv,
    float (*Msh)[7], float* wsh, float* wvsh, float SC2)
{
    const float* wq = Wq + l * 7 * HID;
    const float* wk = Wk + l * 7 * HID;
    if (wt < 49) {
        int c = wt / 7, cp = wt % 7;
        float s = 0.f;
        #pragma unroll 8
        for (int d = 0; d < HID; ++d) s = fmaf(wq[c * HID + d], wk[cp * HID + d], s);
        Msh[c][cp] = s * SC2;
    } else if (wt < 56) {
        int cp = wt - 49;
        float s = 0.f;
        #pragma unroll 8
        for (int d = 0; d < HID; ++d) s = fmaf(bq[l * HID + d], wk[cp * HID + d], s);
        wsh[cp] = s * SC2;
    } else if (wt < 63) {
        wvsh[wt - 56] = Wv[l * 7 + (wt - 56)];
    } else if (wt == 63) {
        wvsh[7] = bv[l];
    }
}

// 512 threads = 8 waves. Thread: 4 query rows (slot+64k) x 1/8 of j (js==wave id).
// h rows packed as 8 fp16 in one float4 -> single ds_read_b128 broadcast per j.
__global__ __launch_bounds__(512, 4) void mlra_kernel(
    const float* __restrict__ power,
    const int*   __restrict__ ele_idx,
    const int*   __restrict__ azi_idx,
    const float* __restrict__ ele_emb,
    const float* __restrict__ azi_emb,
    const float* __restrict__ Wq,
    const float* __restrict__ bq,
    const float* __restrict__ Wk,
    const float* __restrict__ bk,
    const float* __restrict__ Wv,
    const float* __restrict__ bv,
    float* __restrict__ out)
{
    __shared__ float4 hrow[256];   // 8 fp16: [x, e0,e1,e2, a0,a1, a2, 0]; rows 250..255 = 0
    __shared__ float  vsh[256];    // v per row (fp32); pads = 0
    __shared__ float  ps[8][256];  // [j-split][row] partial sum-exp
    __shared__ float  po[8][256];  // [j-split][row] partial sum-exp*v
    __shared__ float  Msh[7][7];
    __shared__ float  wsh[7];
    __shared__ float  wvsh[8];     // wv[0..6], bv in [7]

    const int r    = blockIdx.x;
    const int tid  = threadIdx.x;
    const int slot = tid & 63;    // row slot: rows slot, slot+64, slot+128, slot+192
    const int js   = tid >> 6;    // j-split 0..7 == wave id (wave-uniform)

    // SCALE * log2(e) folded into score constants -> raw exp2
    const float SC2 = 0.17677669529663687f * 1.4426950408889634f;

    // ---- build h rows (fp16-packed), zero pads and vsh ----
    if (tid < 256) {
        float hv[8];
        if (tid < KK) {
            int g = r * KK + tid;
            hv[0] = power[g];
            int ei = ele_idx[g];
            int ai = azi_idx[g];
            hv[1] = ele_emb[ei * 3 + 0];
            hv[2] = ele_emb[ei * 3 + 1];
            hv[3] = ele_emb[ei * 3 + 2];
            hv[4] = azi_emb[ai * 3 + 0];
            hv[5] = azi_emb[ai * 3 + 1];
            hv[6] = azi_emb[ai * 3 + 2];
            hv[7] = 0.f;
        } else {
            #pragma unroll
            for (int c = 0; c < 8; ++c) hv[c] = 0.f;
        }
        float4 f;
        h2 p0; p0.x = (_Float16)hv[0]; p0.y = (_Float16)hv[1];
        h2 p1; p1.x = (_Float16)hv[2]; p1.y = (_Float16)hv[3];
        h2 p2; p2.x = (_Float16)hv[4]; p2.y = (_Float16)hv[5];
        h2 p3; p3.x = (_Float16)hv[6]; p3.y = (_Float16)hv[7];
        f.x = __builtin_bit_cast(float, p0);
        f.y = __builtin_bit_cast(float, p1);
        f.z = __builtin_bit_cast(float, p2);
        f.w = __builtin_bit_cast(float, p3);
        hrow[tid] = f;
        vsh[tid] = 0.f;
    }
    // ---- layer-0 score/v weights on wave 1 (overlaps h build) ----
    if (js == 1) compute_weights(slot, 0, Wq, bq, Wk, bk, Wv, bv, Msh, wsh, wvsh, SC2);
    __syncthreads();   // (a) h + weights(0) ready

    float xout[4] = {0.f, 0.f, 0.f, 0.f};

    for (int l = 0; l < 2; ++l) {
        // ---- t-phase: 4 rows -> fp16 t-pairs; js==0 writes v ----
        h2 t2[4][4];
        #pragma unroll
        for (int k = 0; k < 4; ++k) {
            const int row = slot + 64 * k;
            float4 f = hrow[row];
            h2 h0 = __builtin_bit_cast(h2, f.x);
            h2 h1 = __builtin_bit_cast(h2, f.y);
            h2 h2v = __builtin_bit_cast(h2, f.z);
            h2 h3 = __builtin_bit_cast(h2, f.w);
            float hv[7] = {(float)h0.x, (float)h0.y, (float)h1.x, (float)h1.y,
                           (float)h2v.x, (float)h2v.y, (float)h3.x};
            float tt[8];
            #pragma unroll
            for (int cp = 0; cp < 7; ++cp) {
                float s = wsh[cp];
                #pragma unroll
                for (int c = 0; c < 7; ++c) s = fmaf(hv[c], Msh[c][cp], s);
                tt[cp] = s;
            }
            tt[7] = 0.f;
            #pragma unroll
            for (int c2 = 0; c2 < 4; ++c2) {
                h2 tp; tp.x = (_Float16)tt[2 * c2]; tp.y = (_Float16)tt[2 * c2 + 1];
                t2[k][c2] = tp;
            }
            if (js == 0 && row < KK) {
                float v = wvsh[7];
                #pragma unroll
                for (int c = 0; c < 7; ++c) v = fmaf(hv[c], wvsh[c], v);
                vsh[row] = v;
            }
        }
        __syncthreads();   // (b) v visible

        // ---- main loop: 32 iters, j = js + 8*it (wave-uniform broadcasts) ----
        float ss[4] = {0.f, 0.f, 0.f, 0.f};
        float oo[4] = {0.f, 0.f, 0.f, 0.f};
        #pragma unroll 8
        for (int it = 0; it < 32; ++it) {
            const int j = js + (it << 3);
            float4 f = hrow[j];
            float vj = vsh[j];
            h2 hj0 = __builtin_bit_cast(h2, f.x);
            h2 hj1 = __builtin_bit_cast(h2, f.y);
            h2 hj2 = __builtin_bit_cast(h2, f.z);
            h2 hj3 = __builtin_bit_cast(h2, f.w);
            #pragma unroll
            for (int k = 0; k < 4; ++k) {
                float sc = FDOT2(hj0, t2[k][0],
                           FDOT2(hj1, t2[k][1],
                           FDOT2(hj2, t2[k][2],
                           FDOT2(hj3, t2[k][3], 0.f))));
                float p = EXP2F(sc);
                ss[k] += p;
                oo[k] = fmaf(p, vj, oo[k]);
            }
        }
        // pad correction: js>=2 visited exactly one padded j (score=0 -> p=1, v=0)
        const float corr = (js >= 2) ? 1.0f : 0.0f;
        #pragma unroll
        for (int k = 0; k < 4; ++k) {
            const int row = slot + 64 * k;
            ps[js][row] = ss[k] - corr;
            po[js][row] = oo[k];
        }
        __syncthreads();   // (c) partials ready

        // ---- wave 0: combine + finalize; wave 1: next layer's weights ----
        if (js == 0) {
            #pragma unroll
            for (int k = 0; k < 4; ++k) {
                const int row = slot + 64 * k;
                float s = ((ps[0][row] + ps[1][row]) + (ps[2][row] + ps[3][row]))
                        + ((ps[4][row] + ps[5][row]) + (ps[6][row] + ps[7][row]));
                float o = ((po[0][row] + po[1][row]) + (po[2][row] + po[3][row]))
                        + ((po[4][row] + po[5][row]) + (po[6][row] + po[7][row]));
                float x = o / s;
                xout[k] = x;
                if (l == 0 && row < KK) {
                    // feed layer-1 input: overwrite fp16 slot 0 of the h row
                    reinterpret_cast<_Float16*>(hrow)[row * 8 + 0] = (_Float16)x;
                }
            }
        } else if (js == 1 && l == 0) {
            compute_weights(slot, 1, Wq, bq, Wk, bk, Wv, bv, Msh, wsh, wvsh, SC2);
        }
        __syncthreads();   // (a') x-update + weights(l+1) published
    }

    if (js == 0) {
        #pragma unroll
        for (int k = 0; k < 4; ++k) {
            const int row = slot + 64 * k;
            if (row < KK) out[r * KK + row] = xout[k];
        }
    }
}

extern "C" void kernel_launch(void* const* d_in, const int* in_sizes, int n_in,
                              void* d_out, int out_size, void* d_ws, size_t ws_size,
                              hipStream_t stream) {
    const float* power   = (const float*)d_in[0];
    const int*   ele     = (const int*)d_in[1];
    const int*   azi     = (const int*)d_in[2];
    const float* ele_emb = (const float*)d_in[3];
    const float* azi_emb = (const float*)d_in[4];
    const float* Wq      = (const float*)d_in[5];
    const float* bq      = (const float*)d_in[6];
    const float* Wk      = (const float*)d_in[7];
    const float* bk      = (const float*)d_in[8];
    const float* Wv      = (const float*)d_in[9];
    const float* bv      = (const float*)d_in[10];
    float* outp = (float*)d_out;

    hipLaunchKernelGGL(mlra_kernel, dim3(NR), dim3(512), 0, stream,
                       power, ele, azi, ele_emb, azi_emb, Wq, bq, Wk, bk, Wv, bv, outp);
}